// Round 4
// baseline (914.842 us; speedup 1.0000x reference)
//
#include <hip/hip_runtime.h>

#define FEAT 28   // features per table row
#define LVL  16   // levels
#define HASH_SIZE 524288u          // T_TABLE (power of two for all hashed levels)

typedef float    f32x4 __attribute__((ext_vector_type(4)));
typedef _Float16 f16x8 __attribute__((ext_vector_type(8)));

// ---------------------------------------------------------------------------
// Pack: f32 (total,28) table -> fp16 rows padded to 64B (32 halfs), aligned.
// Row r of packed table lives at ws + r*64 bytes; one 64B line per row.
// Reverse order so the low (first-gathered) levels are L3-hot at gather time.
// ---------------------------------------------------------------------------
__global__ __launch_bounds__(256) void pack_kernel(
    const float* __restrict__ memory, f16x8* __restrict__ wsrow, int nrows)
{
    const int g = blockIdx.x * blockDim.x + threadIdx.x;
    if (g >= nrows) return;
    const int r = nrows - 1 - g;                 // reverse order
    const float* src = memory + (size_t)r * FEAT;
    f16x8 o[4];
#pragma unroll
    for (int k = 0; k < 32; ++k) {
        const float v = (k < FEAT) ? src[k] : 0.0f;
        o[k >> 3][k & 7] = (_Float16)v;          // RN conversion
    }
    f16x8* dst = wsrow + (size_t)r * 4;
#pragma unroll
    for (int k = 0; k < 4; ++k) dst[k] = o[k];
}

// ---------------------------------------------------------------------------
// Gather from packed fp16 table: 4 lanes per (point,level), each lane owns an
// 8-feature slice; 8 independent 16B gathers/thread; each row = one 64B line.
// ---------------------------------------------------------------------------
__global__ __launch_bounds__(256) void gather_packed_kernel(
    const float* __restrict__ inputs,     // (N,3) f32
    const f16x8* __restrict__ wsrow,      // packed table, 4 x f16x8 per row
    const int*   __restrict__ offsets,    // (17) i32
    const int*   __restrict__ res_list,   // (16,3) i32
    const float* __restrict__ side_list,  // (16) f32
    float*       __restrict__ out,        // (N,16,28) f32
    int N)
{
    const int l   = blockIdx.y;
    const int tid = threadIdx.x;
    const int pl  = tid >> 2;             // local point 0..63
    const int j   = tid & 3;              // 8-feature slice 0..3
    const int n   = blockIdx.x * 64 + pl;
    if (n >= N) return;

    const int      base = offsets[l];
    const unsigned size = (unsigned)(offsets[l + 1] - base);
    const int r0 = res_list[l * 3 + 0];
    const int r1 = res_list[l * 3 + 1];
    const int r2 = res_list[l * 3 + 2];
    const float side = side_list[l];

    const float bmin0 = -3.0f, bmin1 = -4.0f, bmin2 = -2.0f;  // BOUNDS[:,0]

    const float x = inputs[n * 3 + 0];
    const float y = inputs[n * 3 + 1];
    const float z = inputs[n * 3 + 2];

    // IEEE division: must match numpy's floor-cell choice bit-for-bit.
    const float p0 = (x - bmin0) / side;
    const float p1 = (y - bmin1) / side;
    const float p2 = (z - bmin2) / side;
    const float g0 = floorf(p0), g1 = floorf(p1), g2 = floorf(p2);
    const float f0 = p0 - g0, f1 = p1 - g1, f2 = p2 - g2;
    const int i0 = (int)g0, i1 = (int)g1, i2 = (int)g2;

    const bool direct = (((float)r0 * (float)r1) * (float)r2) <= (float)size;
    const unsigned ur0   = (unsigned)r0;
    const unsigned ur0r1 = (unsigned)(r0 * r1);

    int   idx8[8];
    float w8[8];
#pragma unroll
    for (int c = 0; c < 8; ++c) {
        const int d0 = (c >> 0) & 1, d1 = (c >> 1) & 1, d2 = (c >> 2) & 1;
        const int c0 = min(max(i0 + d0, 0), r0 - 1);
        const int c1 = min(max(i1 + d1, 0), r1 - 1);
        const int c2 = min(max(i2 + d2, 0), r2 - 1);
        const unsigned u0 = (unsigned)c0, u1 = (unsigned)c1, u2 = (unsigned)c2;
        const unsigned didx = u0 + u1 * ur0 + u2 * ur0r1;
        const unsigned hidx =
            (u0 * 1u ^ u1 * 2654435761u ^ u2 * 805459861u) & (HASH_SIZE - 1u);
        idx8[c] = (int)(direct ? didx : hidx) + base;
        float w = (d0 ? f0 : 1.0f - f0) * (d1 ? f1 : 1.0f - f1);
        w *= (d2 ? f2 : 1.0f - f2);
        w8[c] = w;
    }

    // 8 independent 16B gathers (one per corner); 4 lanes of a point cover
    // exactly the row's single 64B line.
    f16x8 v[8];
#pragma unroll
    for (int c = 0; c < 8; ++c)
        v[c] = wsrow[(size_t)idx8[c] * 4 + j];

    float acc[8];
#pragma unroll
    for (int k = 0; k < 8; ++k) acc[k] = 0.0f;
#pragma unroll
    for (int c = 0; c < 8; ++c) {
        const float w = w8[c];
#pragma unroll
        for (int k = 0; k < 8; ++k) acc[k] += w * (float)v[c][k];
    }

    // lane j holds feats [8j, 8j+8); j==3 only feats 24..27 are real.
    float* op = out + ((size_t)n * LVL + l) * (size_t)FEAT + j * 8;
    f32x4 s0 = { acc[0], acc[1], acc[2], acc[3] };
    __builtin_nontemporal_store(s0, (f32x4*)op);
    if (j < 3) {
        f32x4 s1 = { acc[4], acc[5], acc[6], acc[7] };
        __builtin_nontemporal_store(s1, (f32x4*)(op + 4));
    }
}

// ---------------------------------------------------------------------------
// Fallback (ws too small): R3 kernel — 7 lanes/point, f32 table.
// ---------------------------------------------------------------------------
__global__ __launch_bounds__(448) void hashgrid_f32_kernel(
    const float* __restrict__ inputs, const float* __restrict__ memory,
    const int* __restrict__ offsets, const int* __restrict__ res_list,
    const float* __restrict__ side_list, float* __restrict__ out, int N)
{
    const int l   = blockIdx.y;
    const int tid = threadIdx.x;
    const int pl  = tid / 7;
    const int j   = tid - pl * 7;
    const int n   = blockIdx.x * 64 + pl;
    if (n >= N) return;

    const int      base = offsets[l];
    const unsigned size = (unsigned)(offsets[l + 1] - base);
    const int r0 = res_list[l * 3 + 0];
    const int r1 = res_list[l * 3 + 1];
    const int r2 = res_list[l * 3 + 2];
    const float side = side_list[l];
    const float bmin0 = -3.0f, bmin1 = -4.0f, bmin2 = -2.0f;

    const float x = inputs[n * 3 + 0];
    const float y = inputs[n * 3 + 1];
    const float z = inputs[n * 3 + 2];
    const float p0 = (x - bmin0) / side;
    const float p1 = (y - bmin1) / side;
    const float p2 = (z - bmin2) / side;
    const float g0 = floorf(p0), g1 = floorf(p1), g2 = floorf(p2);
    const float f0 = p0 - g0, f1 = p1 - g1, f2 = p2 - g2;
    const int i0 = (int)g0, i1 = (int)g1, i2 = (int)g2;

    const bool direct = (((float)r0 * (float)r1) * (float)r2) <= (float)size;
    const unsigned ur0   = (unsigned)r0;
    const unsigned ur0r1 = (unsigned)(r0 * r1);

    int idx8[8]; float w8[8];
#pragma unroll
    for (int c = 0; c < 8; ++c) {
        const int d0 = (c >> 0) & 1, d1 = (c >> 1) & 1, d2 = (c >> 2) & 1;
        const int c0 = min(max(i0 + d0, 0), r0 - 1);
        const int c1 = min(max(i1 + d1, 0), r1 - 1);
        const int c2 = min(max(i2 + d2, 0), r2 - 1);
        const unsigned u0 = (unsigned)c0, u1 = (unsigned)c1, u2 = (unsigned)c2;
        const unsigned didx = u0 + u1 * ur0 + u2 * ur0r1;
        const unsigned hidx =
            (u0 * 1u ^ u1 * 2654435761u ^ u2 * 805459861u) % size;
        idx8[c] = (int)(direct ? didx : hidx) + base;
        float w = (d0 ? f0 : 1.0f - f0) * (d1 ? f1 : 1.0f - f1);
        w *= (d2 ? f2 : 1.0f - f2);
        w8[c] = w;
    }
    f32x4 v[8];
#pragma unroll
    for (int c = 0; c < 8; ++c)
        v[c] = ((const f32x4*)(memory + (size_t)idx8[c] * FEAT))[j];
    f32x4 acc = (f32x4)(0.0f);
#pragma unroll
    for (int c = 0; c < 8; ++c) acc += w8[c] * v[c];
    f32x4* op = (f32x4*)(out + ((size_t)n * LVL + l) * (size_t)FEAT) + j;
    __builtin_nontemporal_store(acc, op);
}

extern "C" void kernel_launch(void* const* d_in, const int* in_sizes, int n_in,
                              void* d_out, int out_size, void* d_ws, size_t ws_size,
                              hipStream_t stream) {
    const float* inputs    = (const float*)d_in[0];
    const float* memory    = (const float*)d_in[1];
    const int*   offsets   = (const int*)d_in[2];
    const int*   res_list  = (const int*)d_in[3];
    const float* side_list = (const float*)d_in[4];
    float* out = (float*)d_out;

    const int N     = in_sizes[0] / 3;      // points
    const int nrows = in_sizes[1] / FEAT;   // total table rows (~5.8M)
    const size_t ws_needed = (size_t)nrows * 64;

    if (ws_size >= ws_needed) {
        f16x8* wsrow = (f16x8*)d_ws;
        dim3 pb(256), pg((nrows + 255) / 256);
        hipLaunchKernelGGL(pack_kernel, pg, pb, 0, stream, memory, wsrow, nrows);
        dim3 gb(256), gg((N + 63) / 64, LVL);   // x fastest -> level-major
        hipLaunchKernelGGL(gather_packed_kernel, gg, gb, 0, stream,
                           inputs, wsrow, offsets, res_list, side_list, out, N);
    } else {
        dim3 gb(448), gg((N + 63) / 64, LVL);
        hipLaunchKernelGGL(hashgrid_f32_kernel, gg, gb, 0, stream,
                           inputs, memory, offsets, res_list, side_list, out, N);
    }
}

// Round 5
// 658.701 us; speedup vs baseline: 1.3889x; 1.3889x over previous
//
#include <hip/hip_runtime.h>

#define FEAT 28   // features per table row
#define LVL  16   // levels
#define HASH_SIZE 524288u          // T_TABLE (power of two for all hashed levels)

typedef float    f32x4 __attribute__((ext_vector_type(4)));
typedef _Float16 f16x4 __attribute__((ext_vector_type(4)));
typedef _Float16 f16x8 __attribute__((ext_vector_type(8)));

// ---------------------------------------------------------------------------
// Pack: f32 (total,28) table -> fp16 rows padded to 64B (32 halfs), aligned.
// Row r lives at ws + r*64B; one 64B line per row. Reverse order so the low
// (first-gathered) levels are L3-hot at gather time.
// ---------------------------------------------------------------------------
__global__ __launch_bounds__(256) void pack_kernel(
    const float* __restrict__ memory, f16x8* __restrict__ wsrow, int nrows)
{
    const int g = blockIdx.x * blockDim.x + threadIdx.x;
    if (g >= nrows) return;
    const int r = nrows - 1 - g;                 // reverse order
    const float* src = memory + (size_t)r * FEAT;
    f16x8 o[4];
#pragma unroll
    for (int k = 0; k < 32; ++k) {
        const float v = (k < FEAT) ? src[k] : 0.0f;
        o[k >> 3][k & 7] = (_Float16)v;          // RN conversion
    }
    f16x8* dst = wsrow + (size_t)r * 4;
#pragma unroll
    for (int k = 0; k < 4; ++k) dst[k] = o[k];
}

// ---------------------------------------------------------------------------
// Gather: 8 lanes per point, lane j owns feats [4j,4j+4). Gather granule =
// 8B fp16 == store granule 16B f32 -> no cross-lane shuffle. 2 points per
// thread -> 16 independent 8B gathers in flight. Level-major grid.
// ---------------------------------------------------------------------------
__global__ __launch_bounds__(256) void gather_packed_kernel(
    const float* __restrict__ inputs,     // (N,3) f32
    const f16x4* __restrict__ wsrow,      // packed table, 8 x f16x4 per row
    const int*   __restrict__ offsets,    // (17) i32
    const int*   __restrict__ res_list,   // (16,3) i32
    const float* __restrict__ side_list,  // (16) f32
    float*       __restrict__ out,        // (N,16,28) f32
    int N)
{
    const int l   = blockIdx.y;
    const int tid = threadIdx.x;
    const int pl  = tid >> 3;             // local point 0..31
    const int j   = tid & 7;              // feature slice 0..7 (j==7 is pad)
    const int n0  = blockIdx.x * 64 + pl; // first point
    const int n1  = n0 + 32;              // second point
    if (n0 >= N) return;
    const int n1c = (n1 < N) ? n1 : n0;   // clamp loads; store masked below

    const int      base = offsets[l];
    const unsigned size = (unsigned)(offsets[l + 1] - base);
    const int r0 = res_list[l * 3 + 0];
    const int r1 = res_list[l * 3 + 1];
    const int r2 = res_list[l * 3 + 2];
    const float side = side_list[l];

    const float bmin0 = -3.0f, bmin1 = -4.0f, bmin2 = -2.0f;  // BOUNDS[:,0]

    const bool direct = (((float)r0 * (float)r1) * (float)r2) <= (float)size;
    const unsigned ur0   = (unsigned)r0;
    const unsigned ur0r1 = (unsigned)(r0 * r1);

    int   idx[2][8];
    float w[2][8];
#pragma unroll
    for (int p = 0; p < 2; ++p) {
        const int n = p ? n1c : n0;
        const float x = inputs[n * 3 + 0];
        const float y = inputs[n * 3 + 1];
        const float z = inputs[n * 3 + 2];
        // IEEE division: must match numpy's floor-cell choice bit-for-bit.
        const float p0 = (x - bmin0) / side;
        const float p1 = (y - bmin1) / side;
        const float p2 = (z - bmin2) / side;
        const float g0 = floorf(p0), g1 = floorf(p1), g2 = floorf(p2);
        const float f0 = p0 - g0, f1 = p1 - g1, f2 = p2 - g2;
        const int i0 = (int)g0, i1 = (int)g1, i2 = (int)g2;
#pragma unroll
        for (int c = 0; c < 8; ++c) {
            const int d0 = (c >> 0) & 1, d1 = (c >> 1) & 1, d2 = (c >> 2) & 1;
            const int c0 = min(max(i0 + d0, 0), r0 - 1);
            const int c1 = min(max(i1 + d1, 0), r1 - 1);
            const int c2 = min(max(i2 + d2, 0), r2 - 1);
            const unsigned u0 = (unsigned)c0, u1 = (unsigned)c1,
                           u2 = (unsigned)c2;
            const unsigned didx = u0 + u1 * ur0 + u2 * ur0r1;
            const unsigned hidx =
                (u0 * 1u ^ u1 * 2654435761u ^ u2 * 805459861u) &
                (HASH_SIZE - 1u);
            idx[p][c] = (int)(direct ? didx : hidx) + base;
            float ww = (d0 ? f0 : 1.0f - f0) * (d1 ? f1 : 1.0f - f1);
            ww *= (d2 ? f2 : 1.0f - f2);
            w[p][c] = ww;
        }
    }

    // Issue all 16 independent 8B gathers (8 lanes of a point cover exactly
    // the row's single 64B line).
    f16x4 v[2][8];
#pragma unroll
    for (int c = 0; c < 8; ++c) {
        v[0][c] = wsrow[(size_t)idx[0][c] * 8 + j];
        v[1][c] = wsrow[(size_t)idx[1][c] * 8 + j];
    }

    f32x4 acc0 = (f32x4)(0.0f), acc1 = (f32x4)(0.0f);
#pragma unroll
    for (int c = 0; c < 8; ++c) {
        const float w0 = w[0][c], w1 = w[1][c];
#pragma unroll
        for (int k = 0; k < 4; ++k) {
            acc0[k] += w0 * (float)v[0][c][k];
            acc1[k] += w1 * (float)v[1][c][k];
        }
    }

    // lane j stores feats [4j,4j+4) as one contiguous 16B f32x4 (j==7 = pad).
    if (j < 7) {
        float* op0 = out + ((size_t)n0 * LVL + l) * (size_t)FEAT + j * 4;
        __builtin_nontemporal_store(acc0, (f32x4*)op0);
        if (n1 < N) {
            float* op1 = out + ((size_t)n1 * LVL + l) * (size_t)FEAT + j * 4;
            __builtin_nontemporal_store(acc1, (f32x4*)op1);
        }
    }
}

// ---------------------------------------------------------------------------
// Fallback (ws too small): R3 kernel — 7 lanes/point, f32 table.
// ---------------------------------------------------------------------------
__global__ __launch_bounds__(448) void hashgrid_f32_kernel(
    const float* __restrict__ inputs, const float* __restrict__ memory,
    const int* __restrict__ offsets, const int* __restrict__ res_list,
    const float* __restrict__ side_list, float* __restrict__ out, int N)
{
    const int l   = blockIdx.y;
    const int tid = threadIdx.x;
    const int pl  = tid / 7;
    const int j   = tid - pl * 7;
    const int n   = blockIdx.x * 64 + pl;
    if (n >= N) return;

    const int      base = offsets[l];
    const unsigned size = (unsigned)(offsets[l + 1] - base);
    const int r0 = res_list[l * 3 + 0];
    const int r1 = res_list[l * 3 + 1];
    const int r2 = res_list[l * 3 + 2];
    const float side = side_list[l];
    const float bmin0 = -3.0f, bmin1 = -4.0f, bmin2 = -2.0f;

    const float x = inputs[n * 3 + 0];
    const float y = inputs[n * 3 + 1];
    const float z = inputs[n * 3 + 2];
    const float p0 = (x - bmin0) / side;
    const float p1 = (y - bmin1) / side;
    const float p2 = (z - bmin2) / side;
    const float g0 = floorf(p0), g1 = floorf(p1), g2 = floorf(p2);
    const float f0 = p0 - g0, f1 = p1 - g1, f2 = p2 - g2;
    const int i0 = (int)g0, i1 = (int)g1, i2 = (int)g2;

    const bool direct = (((float)r0 * (float)r1) * (float)r2) <= (float)size;
    const unsigned ur0   = (unsigned)r0;
    const unsigned ur0r1 = (unsigned)(r0 * r1);

    int idx8[8]; float w8[8];
#pragma unroll
    for (int c = 0; c < 8; ++c) {
        const int d0 = (c >> 0) & 1, d1 = (c >> 1) & 1, d2 = (c >> 2) & 1;
        const int c0 = min(max(i0 + d0, 0), r0 - 1);
        const int c1 = min(max(i1 + d1, 0), r1 - 1);
        const int c2 = min(max(i2 + d2, 0), r2 - 1);
        const unsigned u0 = (unsigned)c0, u1 = (unsigned)c1, u2 = (unsigned)c2;
        const unsigned didx = u0 + u1 * ur0 + u2 * ur0r1;
        const unsigned hidx =
            (u0 * 1u ^ u1 * 2654435761u ^ u2 * 805459861u) % size;
        idx8[c] = (int)(direct ? didx : hidx) + base;
        float w = (d0 ? f0 : 1.0f - f0) * (d1 ? f1 : 1.0f - f1);
        w *= (d2 ? f2 : 1.0f - f2);
        w8[c] = w;
    }
    f32x4 v[8];
#pragma unroll
    for (int c = 0; c < 8; ++c)
        v[c] = ((const f32x4*)(memory + (size_t)idx8[c] * FEAT))[j];
    f32x4 acc = (f32x4)(0.0f);
#pragma unroll
    for (int c = 0; c < 8; ++c) acc += w8[c] * v[c];
    f32x4* op = (f32x4*)(out + ((size_t)n * LVL + l) * (size_t)FEAT) + j;
    __builtin_nontemporal_store(acc, op);
}

extern "C" void kernel_launch(void* const* d_in, const int* in_sizes, int n_in,
                              void* d_out, int out_size, void* d_ws, size_t ws_size,
                              hipStream_t stream) {
    const float* inputs    = (const float*)d_in[0];
    const float* memory    = (const float*)d_in[1];
    const int*   offsets   = (const int*)d_in[2];
    const int*   res_list  = (const int*)d_in[3];
    const float* side_list = (const float*)d_in[4];
    float* out = (float*)d_out;

    const int N     = in_sizes[0] / 3;      // points
    const int nrows = in_sizes[1] / FEAT;   // total table rows (~5.8M)
    const size_t ws_needed = (size_t)nrows * 64;

    if (ws_size >= ws_needed) {
        dim3 pb(256), pg((nrows + 255) / 256);
        hipLaunchKernelGGL(pack_kernel, pg, pb, 0, stream,
                           memory, (f16x8*)d_ws, nrows);
        dim3 gb(256), gg((N + 63) / 64, LVL);   // x fastest -> level-major
        hipLaunchKernelGGL(gather_packed_kernel, gg, gb, 0, stream,
                           inputs, (const f16x4*)d_ws, offsets, res_list,
                           side_list, out, N);
    } else {
        dim3 gb(448), gg((N + 63) / 64, LVL);
        hipLaunchKernelGGL(hashgrid_f32_kernel, gg, gb, 0, stream,
                           inputs, memory, offsets, res_list, side_list, out, N);
    }
}